// Round 1
// 742.886 us; speedup vs baseline: 1.3970x; 1.3970x over previous
//
#include <hip/hip_runtime.h>

// Window attention: B=8, C=512 (8 heads x 64 hd), H=W=128, ws=8.
// One block per PAIR of x-adjacent windows (8192 blocks, 512 threads = 8 waves).
// All LDS operands stored as bf16 (converted once at staging):
//   Qs/Ks: [64][132] d-major, rows permuted so S-phase u16 reads are ~conflict-free
//   Vs:    [64][136] d-major (16B-aligned rows -> ds_read_b128 B-fragments)
//   Ps:    [128][64] bf16 row-major, XOR-swizzled cols, aliases Qs
//   Os:    [64][133] f32 (bank-step 5), aliases Qs/Ks/Vs after final barrier
// Global loads/stores are fully-consumed 64B segments (2 windows wide).

typedef __attribute__((ext_vector_type(8))) short short8;
typedef __attribute__((ext_vector_type(4))) float f32x4;

__device__ __forceinline__ unsigned short f2bf(float x) {
    unsigned u = __builtin_bit_cast(unsigned, x);
    u += 0x7fffu + ((u >> 16) & 1u);   // RTNE
    return (unsigned short)(u >> 16);
}

__global__ __launch_bounds__(512, 6) void win_attn(
    const float* __restrict__ qg, const float* __restrict__ kg,
    const float* __restrict__ vg, float* __restrict__ og)
{
    __shared__ alignas(16) char smem[51200];
    unsigned short* Qs = (unsigned short*)smem;     // [64][132] bf16, permuted rows
    unsigned short* Ks = Qs + 64 * 132;             // [64][132] bf16, permuted rows
    unsigned short* Vs = Ks + 64 * 132;             // [64][136] bf16, identity rows
    unsigned short* Ps = (unsigned short*)smem;     // [128][64] bf16, aliases Qs
    float*          Os = (float*)smem;              // [64][133] f32, aliases everything

    const int tid  = threadIdx.x;
    const int lane = tid & 63;
    const int w    = tid >> 6;      // wave 0..7
    const int l16  = lane & 15;
    const int quad = lane >> 4;

    // XCD-chunked swizzle (bijective: 8192 = 8 * 1024)
    const int wid = ((blockIdx.x & 7) << 10) | (blockIdx.x >> 3);
    const int wx8 = wid & 7;              // which pair of windows in x (16 floats wide)
    const int wy  = (wid >> 3) & 15;
    const long base = (long)(wid >> 7) * (64L * 16384) + (long)(wy * 8) * 128 + wx8 * 16;

    // ---- stage Q,K,V global->LDS, f32->bf16 once, 64B-consumed segments ----
    #pragma unroll
    for (int it = 0; it < 4; ++it) {
        int f4 = it * 512 + tid;          // 0..2047 float4s per matrix
        int cq = f4 & 3;                  // 16-float row split in 4 quads
        int r  = (f4 >> 2) & 7;           // spatial row in window
        int d  = f4 >> 5;                 // head-dim channel
        long g = base + (long)d * 16384 + r * 128 + cq * 4;
        float4 a = *(const float4*)(qg + g);
        float4 b = *(const float4*)(kg + g);
        float4 c = *(const float4*)(vg + g);
        // LDS token index: win*64 + r*8 + cx (window-contiguous)
        int tt0 = ((cq >> 1) << 6) + r * 8 + ((cq & 1) << 2);
        // Q/K row permutation: d = kc*32 + quad*8 + j  ->  d' = quad*4 + (j&3) + (j>>2)*16 + kc*32
        int dp  = ((d >> 3) & 3) * 4 + (d & 3) + ((d & 4) << 2) + ((d >> 5) << 5);
        ushort4 uq, uk, uv;
        uq.x = f2bf(a.x * 0.125f); uq.y = f2bf(a.y * 0.125f);
        uq.z = f2bf(a.z * 0.125f); uq.w = f2bf(a.w * 0.125f);
        uk.x = f2bf(b.x); uk.y = f2bf(b.y); uk.z = f2bf(b.z); uk.w = f2bf(b.w);
        uv.x = f2bf(c.x); uv.y = f2bf(c.y); uv.z = f2bf(c.z); uv.w = f2bf(c.w);
        *(ushort4*)(Qs + dp * 132 + tt0) = uq;
        *(ushort4*)(Ks + dp * 132 + tt0) = uk;
        *(ushort4*)(Vs + d  * 136 + tt0) = uv;
    }
    __syncthreads();

    const int win = w >> 2;                       // which of the 2 windows this wave works
    const int qb  = win * 64 + (w & 3) * 16;      // wave's 16 query tokens
    const int kb  = win * 64;                     // window's K/V token base

    // ---- S = Q*K^T : A[m=l16][k=d], B[n=T*16+l16][k=d] ----------------------
    short8 aq[2];
    #pragma unroll
    for (int kc = 0; kc < 2; ++kc)
        #pragma unroll
        for (int j = 0; j < 8; ++j) {
            int dp = quad * 4 + (j & 3) + ((j >> 2) << 4) + (kc << 5);
            aq[kc][j] = (short)Qs[dp * 132 + qb + l16];
        }

    f32x4 accS[4];
    #pragma unroll
    for (int T = 0; T < 4; ++T) accS[T] = (f32x4){0.f, 0.f, 0.f, 0.f};

    #pragma unroll
    for (int T = 0; T < 4; ++T)
        #pragma unroll
        for (int kc = 0; kc < 2; ++kc) {
            short8 bk;
            #pragma unroll
            for (int j = 0; j < 8; ++j) {
                int dp = quad * 4 + (j & 3) + ((j >> 2) << 4) + (kc << 5);
                bk[j] = (short)Ks[dp * 132 + kb + T * 16 + l16];
            }
            accS[T] = __builtin_amdgcn_mfma_f32_16x16x32_bf16(aq[kc], bk, accS[T], 0, 0, 0);
        }

    // ---- softmax (rows quad*4+r live in 16-lane groups) ---------------------
    float p[4][4];
    float invl[4];
    #pragma unroll
    for (int r = 0; r < 4; ++r) {
        float m = fmaxf(fmaxf(accS[0][r], accS[1][r]), fmaxf(accS[2][r], accS[3][r]));
        #pragma unroll
        for (int off = 1; off <= 8; off <<= 1)
            m = fmaxf(m, __shfl_xor(m, off, 64));
        float s = 0.f;
        #pragma unroll
        for (int T = 0; T < 4; ++T) { p[T][r] = __expf(accS[T][r] - m); s += p[T][r]; }
        #pragma unroll
        for (int off = 1; off <= 8; off <<= 1)
            s += __shfl_xor(s, off, 64);
        invl[r] = 1.0f / s;
    }

    __syncthreads();   // all waves done reading Qs/Ks -> Ps may overwrite Qs

    // ---- write P (unnormalized, bf16) XOR-swizzled over Qs ------------------
    #pragma unroll
    for (int T = 0; T < 4; ++T)
        #pragma unroll
        for (int r = 0; r < 4; ++r) {
            int rr = w * 16 + quad * 4 + r;
            int colsw = (T * 16 + l16) ^ ((rr & 7) << 3);
            Ps[rr * 64 + colsw] = f2bf(p[T][r]);
        }
    asm volatile("" ::: "memory");   // order same-wave readback after the writes

    // ---- O = P*V : A=ds_read_b128 from Ps, B=ds_read_b128 from Vs -----------
    f32x4 accO[4];
    #pragma unroll
    for (int T = 0; T < 4; ++T) accO[T] = (f32x4){0.f, 0.f, 0.f, 0.f};

    {
        const int rr = w * 16 + l16;
        const int sw = rr & 7;
        #pragma unroll
        for (int kc = 0; kc < 2; ++kc) {
            int gsw = (kc * 4 + quad) ^ sw;
            short8 ap = *(const short8*)(Ps + rr * 64 + gsw * 8);
            #pragma unroll
            for (int T = 0; T < 4; ++T) {
                short8 bv = *(const short8*)(Vs + (T * 16 + l16) * 136 + kb + kc * 32 + quad * 8);
                accO[T] = __builtin_amdgcn_mfma_f32_16x16x32_bf16(ap, bv, accO[T], 0, 0, 0);
            }
        }
    }

    __syncthreads();   // all P/V reads done before Os overwrites smem

    // ---- O -> LDS f32 d-major (stride 133 -> bank-step 5, <=2-way) ----------
    #pragma unroll
    for (int T = 0; T < 4; ++T)
        #pragma unroll
        for (int r = 0; r < 4; ++r)
            Os[(T * 16 + l16) * 133 + w * 16 + quad * 4 + r] = accO[T][r] * invl[r];

    __syncthreads();

    // ---- coalesced copy-out (64B-consumed segments) -------------------------
    #pragma unroll
    for (int it = 0; it < 4; ++it) {
        int f4 = it * 512 + tid;
        int cq = f4 & 3;
        int r  = (f4 >> 2) & 7;
        int d  = f4 >> 5;
        long g = base + (long)d * 16384 + r * 128 + cq * 4;
        int tt0 = ((cq >> 1) << 6) + r * 8 + ((cq & 1) << 2);
        const float* o = Os + d * 133 + tt0;
        float4 w4;
        w4.x = o[0]; w4.y = o[1]; w4.z = o[2]; w4.w = o[3];
        *(float4*)(og + g) = w4;
    }
}

extern "C" void kernel_launch(void* const* d_in, const int* in_sizes, int n_in,
                              void* d_out, int out_size, void* d_ws, size_t ws_size,
                              hipStream_t stream) {
    (void)in_sizes; (void)n_in; (void)d_ws; (void)ws_size; (void)out_size;
    const float* q = (const float*)d_in[0];
    const float* k = (const float*)d_in[1];
    const float* v = (const float*)d_in[2];
    float* out = (float*)d_out;
    win_attn<<<dim3(8192), dim3(512), 0, stream>>>(q, k, v, out);
}